// Round 1
// baseline (360.817 us; speedup 1.0000x reference)
//
#include <hip/hip_runtime.h>
#include <hip/hip_bf16.h>
#include <stdint.h>

#define B_ROWS 131072
#define DDIM 256
#define TILES_PER_EXPERT 2048   // B_ROWS / 64

typedef short bf16x8 __attribute__((ext_vector_type(8)));
typedef float f32x4 __attribute__((ext_vector_type(4)));

__device__ __forceinline__ unsigned short f32_to_bf16_rne(float f) {
    union { float f; uint32_t u; } v; v.f = f;
    uint32_t u = v.u;
    u += 0x7fffu + ((u >> 16) & 1u);
    return (unsigned short)(u >> 16);
}

// ---------------------------------------------------------------------------
// Kernel 0: prepack all 7 weight matrices (4 leaf, 2 mid, 1 root) into bf16
// MFMA B-fragment order: packed[s][t][lane][j] = W[32s + 8*(lane>>4) + j][16t + (lane&15)]
// 65536 elems per matrix, 458752 total.
// ---------------------------------------------------------------------------
__global__ __launch_bounds__(256) void prepack_weights(
    const float* __restrict__ Wl, const float* __restrict__ Wm,
    const float* __restrict__ Wr, unsigned short* __restrict__ out)
{
    int o = blockIdx.x * 256 + threadIdx.x;     // < 458752 exactly
    int m = o >> 16;
    int w = o & 65535;
    int j = w & 7;
    int l = (w >> 3) & 63;
    int t = (w >> 9) & 15;
    int s = w >> 13;
    int k = 32 * s + 8 * (l >> 4) + j;
    int n = 16 * t + (l & 15);
    const float* src = (m < 4) ? (Wl + m * 65536)
                     : (m < 6) ? (Wm + (m - 4) * 65536)
                               : Wr;
    out[o] = f32_to_bf16_rne(src[k * 256 + n]);
}

// ---------------------------------------------------------------------------
// Kernel 1: gate (fp64 accumulation for exact argmax) + bucket rows by expert.
// 256 threads = 64 rows x 4 k-quarters. perm[e*B + pos] = row.
// ---------------------------------------------------------------------------
__global__ __launch_bounds__(256) void gate_kernel(
    const float* __restrict__ x, const float* __restrict__ Wg,
    const float* __restrict__ bg, int* __restrict__ counts,
    int* __restrict__ perm)
{
    __shared__ float wgl[1024];       // Wg[k][e] flat, 4KB
    __shared__ int hcount[4];
    __shared__ int hbase[4];

    int t = threadIdx.x;
    ((float4*)wgl)[t] = ((const float4*)Wg)[t];
    if (t < 4) hcount[t] = 0;
    __syncthreads();

    int lrow = t >> 2, sub = t & 3;
    int row = blockIdx.x * 64 + lrow;
    const float* xr = x + (long)row * DDIM;

    double a0 = 0.0, a1 = 0.0, a2 = 0.0, a3 = 0.0;
    #pragma unroll
    for (int i = 0; i < 16; i++) {
        int k0 = i * 16 + sub * 4;
        float4 v = *(const float4*)(xr + k0);
        #pragma unroll
        for (int kk = 0; kk < 4; kk++) {
            float xv = (kk == 0) ? v.x : (kk == 1) ? v.y : (kk == 2) ? v.z : v.w;
            const float* wr = wgl + (k0 + kk) * 4;
            a0 += (double)xv * (double)wr[0];
            a1 += (double)xv * (double)wr[1];
            a2 += (double)xv * (double)wr[2];
            a3 += (double)xv * (double)wr[3];
        }
    }
    // reduce across the 4 k-quarter lanes (same wave)
    a0 += __shfl_xor(a0, 1); a0 += __shfl_xor(a0, 2);
    a1 += __shfl_xor(a1, 1); a1 += __shfl_xor(a1, 2);
    a2 += __shfl_xor(a2, 1); a2 += __shfl_xor(a2, 2);
    a3 += __shfl_xor(a3, 1); a3 += __shfl_xor(a3, 2);

    int myidx = 0, mylpos = 0;
    if (sub == 0) {
        double l0 = a0 + (double)bg[0];
        double l1 = a1 + (double)bg[1];
        double l2 = a2 + (double)bg[2];
        double l3 = a3 + (double)bg[3];
        double best = l0; myidx = 0;
        if (l1 > best) { best = l1; myidx = 1; }   // strict > = first-max tiebreak
        if (l2 > best) { best = l2; myidx = 2; }
        if (l3 > best) { best = l3; myidx = 3; }
        mylpos = atomicAdd(&hcount[myidx], 1);
    }
    __syncthreads();
    if (t < 4) hbase[t] = atomicAdd(&counts[t], hcount[t]);
    __syncthreads();
    if (sub == 0) perm[myidx * B_ROWS + hbase[myidx] + mylpos] = row;
}

// ---------------------------------------------------------------------------
// Kernel 2: fused 3-layer MLP per expert bucket. Block = 64 rows, 256 thr.
// LDS X/H buffer in A-fragment-packed layout: [s:8][mt:4][lane:64][j:8] bf16.
// ---------------------------------------------------------------------------
__device__ __forceinline__ void run_level(
    const unsigned short* __restrict__ wp, const float* __restrict__ bias_g,
    unsigned short* apack, f32x4 acc[4][4], float bias[4], int wv, int l)
{
    #pragma unroll
    for (int nt = 0; nt < 4; nt++)
        bias[nt] = bias_g[(4 * wv + nt) * 16 + (l & 15)];
    f32x4 z = {0.f, 0.f, 0.f, 0.f};
    #pragma unroll
    for (int mt = 0; mt < 4; mt++)
        #pragma unroll
        for (int nt = 0; nt < 4; nt++) acc[mt][nt] = z;

    const bf16x8* wpv = (const bf16x8*)wp;
    #pragma unroll
    for (int s = 0; s < 8; s++) {
        bf16x8 a[4], b[4];
        const bf16x8* ap = (const bf16x8*)(apack + s * 4 * 64 * 8);
        #pragma unroll
        for (int mt = 0; mt < 4; mt++) a[mt] = ap[mt * 64 + l];
        #pragma unroll
        for (int nt = 0; nt < 4; nt++) b[nt] = wpv[(s * 16 + 4 * wv + nt) * 64 + l];
        #pragma unroll
        for (int mt = 0; mt < 4; mt++)
            #pragma unroll
            for (int nt = 0; nt < 4; nt++)
                acc[mt][nt] = __builtin_amdgcn_mfma_f32_16x16x32_bf16(
                    a[mt], b[nt], acc[mt][nt], 0, 0, 0);
    }
}

__device__ __forceinline__ void epilogue_lds(
    unsigned short* apack, f32x4 acc[4][4], float bias[4], int wv, int l)
{
    #pragma unroll
    for (int nt = 0; nt < 4; nt++) {
        int col = (4 * wv + nt) * 16 + (l & 15);
        int s = col >> 5;
        int fq = (col >> 3) & 3;
        int j = col & 7;
        #pragma unroll
        for (int mt = 0; mt < 4; mt++) {
            #pragma unroll
            for (int r = 0; r < 4; r++) {
                float v = fmaxf(acc[mt][nt][r] + bias[nt], 0.f);
                int row_l = ((l >> 4) << 2) + r;           // row within 16-tile
                int fl = row_l + 16 * fq;
                apack[((s * 4 + mt) * 64 + fl) * 8 + j] = f32_to_bf16_rne(v);
            }
        }
    }
}

__global__ __launch_bounds__(256, 2) void mlp_kernel(
    const float* __restrict__ x, const unsigned short* __restrict__ wpack,
    const float* __restrict__ b_leaf, const float* __restrict__ b_mid,
    const float* __restrict__ b_root, const int* __restrict__ counts,
    const int* __restrict__ perm, float* __restrict__ out)
{
    __shared__ unsigned short apack[16384];   // 32KB packed A-frags (X, then H1, H2)
    __shared__ int rowsLds[64];

    int e = blockIdx.x >> 11;                 // expert 0..3
    int tile = blockIdx.x & 2047;
    int cnt = counts[e];
    int base = tile * 64;
    if (base >= cnt) return;

    int t = threadIdx.x;
    if (t < 64) {
        int src = base + t;
        if (src >= cnt) src = base;           // dup first valid row for padding
        rowsLds[t] = perm[e * B_ROWS + src];
    }
    __syncthreads();

    // gather X -> LDS in packed A-frag layout (bf16 RNE)
    {
        int lrow = t >> 2, sub = t & 3;
        const float* xr = x + (long)rowsLds[lrow] * DDIM;
        int mt = lrow >> 4;
        int rl = lrow & 15;
        #pragma unroll
        for (int i = 0; i < 16; i++) {
            int k0 = i * 16 + sub * 4;
            float4 v = *(const float4*)(xr + k0);
            int s = k0 >> 5;
            int fl = rl + 16 * ((k0 >> 3) & 3);
            ushort4 u;
            u.x = f32_to_bf16_rne(v.x);
            u.y = f32_to_bf16_rne(v.y);
            u.z = f32_to_bf16_rne(v.z);
            u.w = f32_to_bf16_rne(v.w);
            *(ushort4*)&apack[((s * 4 + mt) * 64 + fl) * 8 + (k0 & 7)] = u;
        }
    }
    __syncthreads();

    int wv = t >> 6, l = t & 63;
    f32x4 acc[4][4];
    float bias[4];

    // level 1: leaf expert e
    run_level(wpack + e * 65536, b_leaf + e * 256, apack, acc, bias, wv, l);
    __syncthreads();
    epilogue_lds(apack, acc, bias, wv, l);
    __syncthreads();

    // level 2: mid expert e>>1
    run_level(wpack + (4 + (e >> 1)) * 65536, b_mid + (e >> 1) * 256, apack, acc, bias, wv, l);
    __syncthreads();
    epilogue_lds(apack, acc, bias, wv, l);
    __syncthreads();

    // level 3: root, scatter-store to global
    run_level(wpack + 6 * 65536, b_root, apack, acc, bias, wv, l);
    #pragma unroll
    for (int nt = 0; nt < 4; nt++) {
        int col = (4 * wv + nt) * 16 + (l & 15);
        #pragma unroll
        for (int mt = 0; mt < 4; mt++) {
            #pragma unroll
            for (int r = 0; r < 4; r++) {
                int row_local = mt * 16 + ((l >> 4) << 2) + r;
                if (base + row_local < cnt) {
                    long grow = rowsLds[row_local];
                    out[grow * DDIM + col] = fmaxf(acc[mt][nt][r] + bias[nt], 0.f);
                }
            }
        }
    }
}

extern "C" void kernel_launch(void* const* d_in, const int* in_sizes, int n_in,
                              void* d_out, int out_size, void* d_ws, size_t ws_size,
                              hipStream_t stream) {
    const float* x      = (const float*)d_in[0];
    const float* Wg     = (const float*)d_in[1];
    const float* bg     = (const float*)d_in[2];
    const float* W_leaf = (const float*)d_in[3];
    const float* b_leaf = (const float*)d_in[4];
    const float* W_mid  = (const float*)d_in[5];
    const float* b_mid  = (const float*)d_in[6];
    const float* W_root = (const float*)d_in[7];
    const float* b_root = (const float*)d_in[8];
    float* out = (float*)d_out;

    char* ws = (char*)d_ws;
    int* counts = (int*)ws;                                   // 16 B
    int* perm = (int*)(ws + 256);                             // 4*B*4 = 2 MB
    unsigned short* wpack = (unsigned short*)(ws + (4 << 20)); // 896 KB

    hipMemsetAsync(counts, 0, 16, stream);
    prepack_weights<<<1792, 256, 0, stream>>>(W_leaf, W_mid, W_root, wpack);
    gate_kernel<<<B_ROWS / 64, 256, 0, stream>>>(x, Wg, bg, counts, perm);
    mlp_kernel<<<4 * TILES_PER_EXPERT, 256, 0, stream>>>(
        x, wpack, b_leaf, b_mid, b_root, counts, perm, out);
}